// Round 6
// baseline (323.106 us; speedup 1.0000x reference)
//
#include <hip/hip_runtime.h>
#include <hip/hip_bf16.h>
#include <math.h>

#define N_NODES 50000
#define N_EDGES 800000
#define D_IN 256
#define D_HID 256
#define D_OUT 128

typedef unsigned short ushort_t;
typedef __attribute__((ext_vector_type(8))) short bf16x8;
typedef __attribute__((ext_vector_type(4))) float f32x4;

__device__ inline float bf2f(ushort_t u) {
    union { unsigned int i; float f; } v; v.i = ((unsigned int)u) << 16; return v.f;
}
__device__ inline ushort_t f2bf(float f) {
    __hip_bfloat16 h = __float2bfloat16(f);  // RNE
    return *reinterpret_cast<ushort_t*>(&h);
}
// bf16 pair unpack: lo = bits<<16, hi = bits&0xffff0000 (1 VALU op each)
__device__ inline float blo(unsigned u) {
    union { unsigned i; float f; } v; v.i = u << 16; return v.f;
}
__device__ inline float bhi(unsigned u) {
    union { unsigned i; float f; } v; v.i = u & 0xffff0000u; return v.f;
}
__device__ inline unsigned pack2bf(float a, float b) {
    return (unsigned)f2bf(a) | ((unsigned)f2bf(b) << 16);
}

// ================= degree =================

__global__ void k_count(const int* __restrict__ dst, int* __restrict__ degI, int e) {
    int i = blockIdx.x * 256 + threadIdx.x;
    if (i < e) atomicAdd(&degI[dst[i]], 1);
}

// ================= scan over PADDED degrees (pad to multiple of 16) =================

__global__ void k_block_sums(const int* __restrict__ degI, int* __restrict__ bsum, int n) {
    __shared__ int s[256];
    int i = blockIdx.x * 256 + threadIdx.x;
    int v = 0;
    if (i < n) v = (degI[i] + 15) & ~15;
    s[threadIdx.x] = v;
    __syncthreads();
    for (int st = 128; st > 0; st >>= 1) {
        if (threadIdx.x < st) s[threadIdx.x] += s[threadIdx.x + st];
        __syncthreads();
    }
    if (threadIdx.x == 0) bsum[blockIdx.x] = s[0];
}

__global__ void k_scan_bsums(int* __restrict__ bsum, int nb) {
    __shared__ int s[256];
    int t = threadIdx.x;
    s[t] = (t < nb) ? bsum[t] : 0;
    __syncthreads();
    for (int off = 1; off < 256; off <<= 1) {
        int v = 0;
        if (t >= off) v = s[t - off];
        __syncthreads();
        if (t >= off) s[t] += v;
        __syncthreads();
    }
    if (t < nb) bsum[t] = (t == 0) ? 0 : s[t - 1];
}

// computes offs/cursor/dinv AND fills padding slots with zero-row index
__global__ void k_scan_apply(const int* __restrict__ degI, const int* __restrict__ bsum,
                             int* __restrict__ offs, int* __restrict__ cursor,
                             float* __restrict__ dinv, int* __restrict__ ebuf, int n) {
    __shared__ int s[256];
    int t = threadIdx.x;
    int i = blockIdx.x * 256 + t;
    int deg = (i < n) ? degI[i] : 0;
    int v = (deg + 15) & ~15;
    s[t] = v;
    __syncthreads();
    for (int off = 1; off < 256; off <<= 1) {
        int u = 0;
        if (t >= off) u = s[t - off];
        __syncthreads();
        if (t >= off) s[t] += u;
        __syncthreads();
    }
    int excl = s[t] - v + bsum[blockIdx.x];
    if (i < n) {
        offs[i] = excl;
        cursor[i] = excl;
        dinv[i] = rsqrtf((float)(1 + deg));
        for (int p = excl + deg; p < excl + v; ++p) ebuf[p] = N_NODES;
        if (i == n - 1) offs[n] = excl + v;
    }
}

__global__ void k_fill(const int* __restrict__ src, const int* __restrict__ dst,
                       int* __restrict__ cursor, int* __restrict__ ebuf, int e) {
    int i = blockIdx.x * 256 + threadIdx.x;
    if (i < e) {
        int d = dst[i];
        int pos = atomicAdd(&cursor[d], 1);
        ebuf[pos] = src[i];
    }
}

// ================= weight transpose+convert + zero-row init =================

__global__ void k_convW(const float* __restrict__ W1, const float* __restrict__ W2,
                        ushort_t* __restrict__ Wt1, ushort_t* __restrict__ Wt2,
                        ushort_t* __restrict__ h1z, ushort_t* __restrict__ h2z) {
    int i = blockIdx.x * 256 + threadIdx.x;
    const int n1 = D_IN * D_HID;       // 65536
    const int n2 = D_HID * D_OUT;      // 32768
    if (i < n1) {
        int k = i / D_HID, n = i % D_HID;
        Wt1[(size_t)n * D_IN + k] = f2bf(W1[i]);
    } else if (i < n1 + n2) {
        int j = i - n1;
        int k = j / D_OUT, n = j % D_OUT;
        Wt2[(size_t)n * D_HID + k] = f2bf(W2[j]);
    } else {
        int j = i - n1 - n2;
        if (j < D_HID) h1z[j] = 0;
        else if (j < D_HID + D_OUT) h2z[j - D_HID] = 0;
    }
}

// ================= bf16 MFMA GEMM with dinv-scaled epilogue =================
// C[M,N](bf16) = (A[M,K] * Bt[N,K]^T) * dinv[row]; 128x128 tile, 4 waves, BK=32.

template <bool A_IS_BF16>
__global__ __launch_bounds__(256) void k_gemm_mfma(const void* __restrict__ Av,
                                                   const ushort_t* __restrict__ Bt,
                                                   const float* __restrict__ dinvD,
                                                   ushort_t* __restrict__ C,
                                                   int M, int K, int N) {
    __shared__ ushort_t As[128 * 40];
    __shared__ ushort_t Bs[128 * 40];

    const int t = threadIdx.x;
    const int lane = t & 63;
    const int w = t >> 6;
    const int wr = w >> 1, wc = w & 1;
    const int m0 = blockIdx.x * 128;
    const int n0 = blockIdx.y * 128;

    const int srow = t >> 1;
    const int scol = (t & 1) * 16;

    f32x4 acc[4][4];
#pragma unroll
    for (int m = 0; m < 4; ++m)
#pragma unroll
        for (int n = 0; n < 4; ++n)
#pragma unroll
            for (int i = 0; i < 4; ++i) acc[m][n][i] = 0.0f;

    for (int kt = 0; kt < K; kt += 32) {
        const int gr = m0 + srow;
        if (A_IS_BF16) {
            const ushort_t* A = (const ushort_t*)Av;
            uint4 v0 = make_uint4(0, 0, 0, 0), v1 = make_uint4(0, 0, 0, 0);
            if (gr < M) {
                const uint4* p = (const uint4*)(A + (size_t)gr * K + kt + scol);
                v0 = p[0]; v1 = p[1];
            }
            *(uint4*)&As[srow * 40 + scol] = v0;
            *(uint4*)&As[srow * 40 + scol + 8] = v1;
        } else {
            const float* A = (const float*)Av;
#pragma unroll
            for (int i = 0; i < 4; ++i) {
                float4 v = make_float4(0.f, 0.f, 0.f, 0.f);
                if (gr < M) v = *(const float4*)(A + (size_t)gr * K + kt + scol + 4 * i);
                ushort4 u;
                u.x = f2bf(v.x); u.y = f2bf(v.y); u.z = f2bf(v.z); u.w = f2bf(v.w);
                *(ushort4*)&As[srow * 40 + scol + 4 * i] = u;
            }
        }
        {
            const uint4* p = (const uint4*)(Bt + (size_t)(n0 + srow) * K + kt + scol);
            uint4 v0 = p[0], v1 = p[1];
            *(uint4*)&Bs[srow * 40 + scol] = v0;
            *(uint4*)&Bs[srow * 40 + scol + 8] = v1;
        }
        __syncthreads();

        const int kg = (lane >> 4) * 8;
        const int lr = lane & 15;
        bf16x8 a[4], b[4];
#pragma unroll
        for (int m = 0; m < 4; ++m)
            a[m] = *(const bf16x8*)&As[(wr * 64 + m * 16 + lr) * 40 + kg];
#pragma unroll
        for (int n = 0; n < 4; ++n)
            b[n] = *(const bf16x8*)&Bs[(wc * 64 + n * 16 + lr) * 40 + kg];
#pragma unroll
        for (int m = 0; m < 4; ++m)
#pragma unroll
            for (int n = 0; n < 4; ++n)
                acc[m][n] = __builtin_amdgcn_mfma_f32_16x16x32_bf16(a[m], b[n], acc[m][n], 0, 0, 0);
        __syncthreads();
    }

    const int lr = lane & 15;
    const int rg = (lane >> 4) * 4;
#pragma unroll
    for (int m = 0; m < 4; ++m) {
        const int rb = m0 + wr * 64 + m * 16 + rg;
#pragma unroll
        for (int i = 0; i < 4; ++i) {
            const int row = rb + i;
            if (row < M) {
                const float dr = dinvD[row];
#pragma unroll
                for (int n = 0; n < 4; ++n) {
                    const int col = n0 + wc * 64 + n * 16 + lr;
                    C[(size_t)row * N + col] = f2bf(acc[m][n][i] * dr);
                }
            }
        }
    }
}

// ================= half-wave pipelined CSR gather =================
// out[node] = F(dinv[node] * (h'[node] + sum_e h'[src_e]) + bias)
// Edge lists padded to multiples of 16 with the zero row.
// Lanes 0-31 take even edges, lanes 32-63 take odd edges; each lane loads
// 16B (DIM=256) / 8B (DIM=128) -> one row per half-wave, 2 edges per instr.
// Cross-half merge once per node via shfl_xor(32).
// MODE 0: F = relu, bf16 out. MODE 1: F = sigmoid, f32 out.

__device__ inline void ld_idx16(const int* __restrict__ p, int* s) {
    int4 a = ((const int4*)p)[0];
    int4 b = ((const int4*)p)[1];
    int4 c = ((const int4*)p)[2];
    int4 d = ((const int4*)p)[3];
    s[0]  = __builtin_amdgcn_readfirstlane(a.x);
    s[1]  = __builtin_amdgcn_readfirstlane(a.y);
    s[2]  = __builtin_amdgcn_readfirstlane(a.z);
    s[3]  = __builtin_amdgcn_readfirstlane(a.w);
    s[4]  = __builtin_amdgcn_readfirstlane(b.x);
    s[5]  = __builtin_amdgcn_readfirstlane(b.y);
    s[6]  = __builtin_amdgcn_readfirstlane(b.z);
    s[7]  = __builtin_amdgcn_readfirstlane(b.w);
    s[8]  = __builtin_amdgcn_readfirstlane(c.x);
    s[9]  = __builtin_amdgcn_readfirstlane(c.y);
    s[10] = __builtin_amdgcn_readfirstlane(c.z);
    s[11] = __builtin_amdgcn_readfirstlane(c.w);
    s[12] = __builtin_amdgcn_readfirstlane(d.x);
    s[13] = __builtin_amdgcn_readfirstlane(d.y);
    s[14] = __builtin_amdgcn_readfirstlane(d.z);
    s[15] = __builtin_amdgcn_readfirstlane(d.w);
}

template <int DIM, int MODE>
__global__ __launch_bounds__(256) void k_gather_bf(const ushort_t* __restrict__ h,
                                                   const float* __restrict__ dinv,
                                                   const int* __restrict__ offs,
                                                   const int* __restrict__ ebuf,
                                                   const float* __restrict__ bias,
                                                   void* __restrict__ outv, int n) {
    constexpr int PL = DIM / 32;  // elems per lane: 8 (DIM=256) or 4 (DIM=128)
    const int node = (blockIdx.x * 256 + threadIdx.x) >> 6;
    const int lane = threadIdx.x & 63;
    if (node >= n) return;

    const int sub = lane & 31;
    const int hsel = lane & 32;     // 0 for half 0, 32 for half 1
    const int base = sub * PL;
    const ushort_t* hb = h + base;

    float acc[PL];
#pragma unroll
    for (int j = 0; j < PL; ++j) acc[j] = 0.0f;
    if (hsel == 0) {  // self row counted once, in half 0
        if (PL == 8) {
            uint4 u = *(const uint4*)(hb + (size_t)node * DIM);
            acc[0] = blo(u.x); acc[1] = bhi(u.x); acc[2] = blo(u.y); acc[3] = bhi(u.y);
            acc[4] = blo(u.z); acc[5] = bhi(u.z); acc[6] = blo(u.w); acc[7] = bhi(u.w);
        } else {
            uint2 u = *(const uint2*)(hb + (size_t)node * DIM);
            acc[0] = blo(u.x); acc[1] = bhi(u.x); acc[2] = blo(u.y); acc[3] = bhi(u.y);
        }
    }

    int e = __builtin_amdgcn_readfirstlane(offs[node]);
    const int e1 = __builtin_amdgcn_readfirstlane(offs[node + 1]);

    int cs[16], ns[16];
    bool have = e < e1;
    if (have) ld_idx16(ebuf + e, cs);

    while (have) {
        const int en = e + 16;
        const bool hn = en < e1;
        if (PL == 8) {
            uint4 u[8];
#pragma unroll
            for (int i = 0; i < 8; ++i) {
                const int sidx = hsel ? cs[2 * i + 1] : cs[2 * i];
                u[i] = *(const uint4*)(hb + (size_t)sidx * DIM);
            }
            if (hn) ld_idx16(ebuf + en, ns);
#pragma unroll
            for (int i = 0; i < 8; ++i) {
                acc[0] += blo(u[i].x); acc[1] += bhi(u[i].x);
                acc[2] += blo(u[i].y); acc[3] += bhi(u[i].y);
                acc[4] += blo(u[i].z); acc[5] += bhi(u[i].z);
                acc[6] += blo(u[i].w); acc[7] += bhi(u[i].w);
            }
        } else {
            uint2 u[8];
#pragma unroll
            for (int i = 0; i < 8; ++i) {
                const int sidx = hsel ? cs[2 * i + 1] : cs[2 * i];
                u[i] = *(const uint2*)(hb + (size_t)sidx * DIM);
            }
            if (hn) ld_idx16(ebuf + en, ns);
#pragma unroll
            for (int i = 0; i < 8; ++i) {
                acc[0] += blo(u[i].x); acc[1] += bhi(u[i].x);
                acc[2] += blo(u[i].y); acc[3] += bhi(u[i].y);
            }
        }
        e = en; have = hn;
#pragma unroll
        for (int j = 0; j < 16; ++j) cs[j] = ns[j];
    }

    // merge halves
#pragma unroll
    for (int j = 0; j < PL; ++j) acc[j] += __shfl_xor(acc[j], 32);

    if (hsel == 0) {
        const float di = dinv[node];
        if (MODE == 0) {  // bf16 relu (PL==8)
            unsigned wout[PL / 2];
#pragma unroll
            for (int j = 0; j < PL; j += 2) {
                const float v0 = fmaxf(di * acc[j] + bias[base + j], 0.f);
                const float v1 = fmaxf(di * acc[j + 1] + bias[base + j + 1], 0.f);
                wout[j / 2] = pack2bf(v0, v1);
            }
            ushort_t* out = (ushort_t*)outv;
            if (PL == 8)
                *(uint4*)(out + (size_t)node * DIM + base) = *(uint4*)wout;
            else
                *(uint2*)(out + (size_t)node * DIM + base) = *(uint2*)wout;
        } else {  // f32 sigmoid (PL==4)
            float vout[PL];
#pragma unroll
            for (int j = 0; j < PL; ++j) {
                const float v = di * acc[j] + bias[base + j];
                vout[j] = 1.0f / (1.0f + expf(-v));
            }
            float* out = (float*)outv;
            if (PL == 4)
                *(float4*)(out + (size_t)node * DIM + base) = *(float4*)vout;
            else {
#pragma unroll
                for (int j = 0; j < PL; ++j) out[(size_t)node * DIM + base + j] = vout[j];
            }
        }
    }
}

// ================= launch =================

extern "C" void kernel_launch(void* const* d_in, const int* in_sizes, int n_in,
                              void* d_out, int out_size, void* d_ws, size_t ws_size,
                              hipStream_t stream) {
    const float* x  = (const float*)d_in[0];
    const int*   ei = (const int*)d_in[1];
    const float* W1 = (const float*)d_in[2];
    const float* b1 = (const float*)d_in[3];
    const float* W2 = (const float*)d_in[4];
    const float* b2 = (const float*)d_in[5];
    float* out = (float*)d_out;

    float* wsf    = (float*)d_ws;
    float* dinv   = wsf;                            // [50048] f32
    int*   degI   = (int*)(wsf + 50048);            // [50048]
    int*   offs   = degI + 50048;                   // [50064] (uses 50001)
    int*   cursor = offs + 50064;                   // [50048]
    int*   bsum   = cursor + 50048;                 // [256]
    int*   ebuf   = bsum + 256;                     // [1600000] padded CSR (<=1.55M used)
    ushort_t* Wt1 = (ushort_t*)(ebuf + 1600000);    // [65536] bf16
    ushort_t* Wt2 = Wt1 + 65536;                    // [32768] bf16
    ushort_t* h1  = Wt2 + 32768;                    // [50048*256] bf16, row 50000 = zeros
    ushort_t* agg1= h1 + (size_t)50048 * D_HID;     // [50048*256] bf16
    ushort_t* h2  = agg1 + (size_t)50048 * D_HID;   // [50048*128] bf16, row 50000 = zeros

    const int* src = ei;
    const int* dst = ei + N_EDGES;

    const int blocksN = (N_NODES + 255) / 256;  // 196
    const int blocksE = (N_EDGES + 255) / 256;

    // ---- CSR build (padded to 16) + norms ----
    hipMemsetAsync(degI, 0, N_NODES * sizeof(int), stream);
    k_count<<<blocksE, 256, 0, stream>>>(dst, degI, N_EDGES);
    k_block_sums<<<blocksN, 256, 0, stream>>>(degI, bsum, N_NODES);
    k_scan_bsums<<<1, 256, 0, stream>>>(bsum, blocksN);
    k_scan_apply<<<blocksN, 256, 0, stream>>>(degI, bsum, offs, cursor, dinv, ebuf, N_NODES);
    k_fill<<<blocksE, 256, 0, stream>>>(src, dst, cursor, ebuf, N_EDGES);

    // ---- weights + zero rows ----
    {
        const int tot = D_IN * D_HID + D_HID * D_OUT + D_HID + D_OUT;
        k_convW<<<(tot + 255) / 256, 256, 0, stream>>>(W1, W2, Wt1, Wt2,
                                                       h1 + (size_t)N_NODES * D_HID,
                                                       h2 + (size_t)N_NODES * D_OUT);
    }

    // ---- layer 1 GEMM: h1 = bf16((x @ W1) * dinv[row]) ----
    {
        dim3 g((N_NODES + 127) / 128, D_HID / 128);
        k_gemm_mfma<false><<<g, 256, 0, stream>>>(x, Wt1, dinv, h1, N_NODES, D_IN, D_HID);
    }

    // ---- aggregate 256-dim: agg1 = bf16(relu(dinv*(sum) + b1)) ----
    k_gather_bf<D_HID, 0><<<(N_NODES * 64 + 255) / 256, 256, 0, stream>>>(
        h1, dinv, offs, ebuf, b1, agg1, N_NODES);

    // ---- layer 2 GEMM: h2 = bf16((agg1 @ W2) * dinv[row]) ----
    {
        dim3 g((N_NODES + 127) / 128, D_OUT / 128);
        k_gemm_mfma<true><<<g, 256, 0, stream>>>(agg1, Wt2, dinv, h2, N_NODES, D_HID, D_OUT);
    }

    // ---- aggregate 128-dim: out = sigmoid(dinv*(sum) + b2) ----
    k_gather_bf<D_OUT, 1><<<(N_NODES * 64 + 255) / 256, 256, 0, stream>>>(
        h2, dinv, offs, ebuf, b2, out, N_NODES);
}

// Round 7
// 280.786 us; speedup vs baseline: 1.1507x; 1.1507x over previous
//
#include <hip/hip_runtime.h>
#include <hip/hip_bf16.h>
#include <math.h>

#define N_NODES 50000
#define N_EDGES 800000
#define D_IN 256
#define D_HID 256
#define D_OUT 128

typedef unsigned short ushort_t;
typedef __attribute__((ext_vector_type(8))) short bf16x8;
typedef __attribute__((ext_vector_type(4))) float f32x4;

__device__ inline ushort_t f2bf(float f) {
    __hip_bfloat16 h = __float2bfloat16(f);  // RNE
    return *reinterpret_cast<ushort_t*>(&h);
}
// bf16 pair unpack: lo = bits<<16, hi = bits&0xffff0000 (1 VALU op each)
__device__ inline float blo(unsigned u) {
    union { unsigned i; float f; } v; v.i = u << 16; return v.f;
}
__device__ inline float bhi(unsigned u) {
    union { unsigned i; float f; } v; v.i = u & 0xffff0000u; return v.f;
}
__device__ inline unsigned pack2bf(float a, float b) {
    return (unsigned)f2bf(a) | ((unsigned)f2bf(b) << 16);
}

// ================= degree =================

__global__ void k_count(const int* __restrict__ dst, int* __restrict__ degI, int e) {
    int i = blockIdx.x * 256 + threadIdx.x;
    if (i < e) atomicAdd(&degI[dst[i]], 1);
}

// ================= scan over PADDED degrees (pad to multiple of 16) =================

__global__ void k_block_sums(const int* __restrict__ degI, int* __restrict__ bsum, int n) {
    __shared__ int s[256];
    int i = blockIdx.x * 256 + threadIdx.x;
    int v = 0;
    if (i < n) v = (degI[i] + 15) & ~15;
    s[threadIdx.x] = v;
    __syncthreads();
    for (int st = 128; st > 0; st >>= 1) {
        if (threadIdx.x < st) s[threadIdx.x] += s[threadIdx.x + st];
        __syncthreads();
    }
    if (threadIdx.x == 0) bsum[blockIdx.x] = s[0];
}

__global__ void k_scan_bsums(int* __restrict__ bsum, int nb) {
    __shared__ int s[256];
    int t = threadIdx.x;
    s[t] = (t < nb) ? bsum[t] : 0;
    __syncthreads();
    for (int off = 1; off < 256; off <<= 1) {
        int v = 0;
        if (t >= off) v = s[t - off];
        __syncthreads();
        if (t >= off) s[t] += v;
        __syncthreads();
    }
    if (t < nb) bsum[t] = (t == 0) ? 0 : s[t - 1];
}

// computes offs/cursor/dinv AND fills padding slots with zero-row index
__global__ void k_scan_apply(const int* __restrict__ degI, const int* __restrict__ bsum,
                             int* __restrict__ offs, int* __restrict__ cursor,
                             float* __restrict__ dinv, int* __restrict__ ebuf, int n) {
    __shared__ int s[256];
    int t = threadIdx.x;
    int i = blockIdx.x * 256 + t;
    int deg = (i < n) ? degI[i] : 0;
    int v = (deg + 15) & ~15;
    s[t] = v;
    __syncthreads();
    for (int off = 1; off < 256; off <<= 1) {
        int u = 0;
        if (t >= off) u = s[t - off];
        __syncthreads();
        if (t >= off) s[t] += u;
        __syncthreads();
    }
    int excl = s[t] - v + bsum[blockIdx.x];
    if (i < n) {
        offs[i] = excl;
        cursor[i] = excl;
        dinv[i] = rsqrtf((float)(1 + deg));
        for (int p = excl + deg; p < excl + v; ++p) ebuf[p] = N_NODES;
        if (i == n - 1) offs[n] = excl + v;
    }
}

__global__ void k_fill(const int* __restrict__ src, const int* __restrict__ dst,
                       int* __restrict__ cursor, int* __restrict__ ebuf, int e) {
    int i = blockIdx.x * 256 + threadIdx.x;
    if (i < e) {
        int d = dst[i];
        int pos = atomicAdd(&cursor[d], 1);
        ebuf[pos] = src[i];
    }
}

// ================= weight transpose+convert + zero-row init =================

__global__ void k_convW(const float* __restrict__ W1, const float* __restrict__ W2,
                        ushort_t* __restrict__ Wt1, ushort_t* __restrict__ Wt2,
                        ushort_t* __restrict__ h1z, ushort_t* __restrict__ h2z) {
    int i = blockIdx.x * 256 + threadIdx.x;
    const int n1 = D_IN * D_HID;       // 65536
    const int n2 = D_HID * D_OUT;      // 32768
    if (i < n1) {
        int k = i / D_HID, n = i % D_HID;
        Wt1[(size_t)n * D_IN + k] = f2bf(W1[i]);
    } else if (i < n1 + n2) {
        int j = i - n1;
        int k = j / D_OUT, n = j % D_OUT;
        Wt2[(size_t)n * D_HID + k] = f2bf(W2[j]);
    } else {
        int j = i - n1 - n2;
        if (j < D_HID) h1z[j] = 0;
        else if (j < D_HID + D_OUT) h2z[j - D_HID] = 0;
    }
}

// ================= bf16 MFMA GEMM with dinv-scaled epilogue =================
// C[M,N](bf16) = (A[M,K] * Bt[N,K]^T) * dinv[row]; 128x128 tile, 4 waves, BK=32.

template <bool A_IS_BF16>
__global__ __launch_bounds__(256) void k_gemm_mfma(const void* __restrict__ Av,
                                                   const ushort_t* __restrict__ Bt,
                                                   const float* __restrict__ dinvD,
                                                   ushort_t* __restrict__ C,
                                                   int M, int K, int N) {
    __shared__ ushort_t As[128 * 40];
    __shared__ ushort_t Bs[128 * 40];

    const int t = threadIdx.x;
    const int lane = t & 63;
    const int w = t >> 6;
    const int wr = w >> 1, wc = w & 1;
    const int m0 = blockIdx.x * 128;
    const int n0 = blockIdx.y * 128;

    const int srow = t >> 1;
    const int scol = (t & 1) * 16;

    f32x4 acc[4][4];
#pragma unroll
    for (int m = 0; m < 4; ++m)
#pragma unroll
        for (int n = 0; n < 4; ++n)
#pragma unroll
            for (int i = 0; i < 4; ++i) acc[m][n][i] = 0.0f;

    for (int kt = 0; kt < K; kt += 32) {
        const int gr = m0 + srow;
        if (A_IS_BF16) {
            const ushort_t* A = (const ushort_t*)Av;
            uint4 v0 = make_uint4(0, 0, 0, 0), v1 = make_uint4(0, 0, 0, 0);
            if (gr < M) {
                const uint4* p = (const uint4*)(A + (size_t)gr * K + kt + scol);
                v0 = p[0]; v1 = p[1];
            }
            *(uint4*)&As[srow * 40 + scol] = v0;
            *(uint4*)&As[srow * 40 + scol + 8] = v1;
        } else {
            const float* A = (const float*)Av;
#pragma unroll
            for (int i = 0; i < 4; ++i) {
                float4 v = make_float4(0.f, 0.f, 0.f, 0.f);
                if (gr < M) v = *(const float4*)(A + (size_t)gr * K + kt + scol + 4 * i);
                ushort4 u;
                u.x = f2bf(v.x); u.y = f2bf(v.y); u.z = f2bf(v.z); u.w = f2bf(v.w);
                *(ushort4*)&As[srow * 40 + scol + 4 * i] = u;
            }
        }
        {
            const uint4* p = (const uint4*)(Bt + (size_t)(n0 + srow) * K + kt + scol);
            uint4 v0 = p[0], v1 = p[1];
            *(uint4*)&Bs[srow * 40 + scol] = v0;
            *(uint4*)&Bs[srow * 40 + scol + 8] = v1;
        }
        __syncthreads();

        const int kg = (lane >> 4) * 8;
        const int lr = lane & 15;
        bf16x8 a[4], b[4];
#pragma unroll
        for (int m = 0; m < 4; ++m)
            a[m] = *(const bf16x8*)&As[(wr * 64 + m * 16 + lr) * 40 + kg];
#pragma unroll
        for (int n = 0; n < 4; ++n)
            b[n] = *(const bf16x8*)&Bs[(wc * 64 + n * 16 + lr) * 40 + kg];
#pragma unroll
        for (int m = 0; m < 4; ++m)
#pragma unroll
            for (int n = 0; n < 4; ++n)
                acc[m][n] = __builtin_amdgcn_mfma_f32_16x16x32_bf16(a[m], b[n], acc[m][n], 0, 0, 0);
        __syncthreads();
    }

    const int lr = lane & 15;
    const int rg = (lane >> 4) * 4;
#pragma unroll
    for (int m = 0; m < 4; ++m) {
        const int rb = m0 + wr * 64 + m * 16 + rg;
#pragma unroll
        for (int i = 0; i < 4; ++i) {
            const int row = rb + i;
            if (row < M) {
                const float dr = dinvD[row];
#pragma unroll
                for (int n = 0; n < 4; ++n) {
                    const int col = n0 + wc * 64 + n * 16 + lr;
                    C[(size_t)row * N + col] = f2bf(acc[m][n][i] * dr);
                }
            }
        }
    }
}

// ================= sliced CSR gather (XCD-pinned column slices) =================
// out[node][slice] = F(dinv[node] * (h'[node] + sum_e h'[src_e]) + bias)[slice]
// Slice = 32 dims = 64B = 1 cache line per edge. slice = blockIdx.x % NSLICE
// so (with rr block->XCD dispatch) each XCD's L2 holds one 3.2MB h-slice.
// One node per 16-lane group (16 nodes/block); no cross-lane ops, no LDS.
// 8-edge unroll -> 8 idx + 8 row loads in flight per group.
// MODE 0: F = relu, bf16 out. MODE 1: F = sigmoid, f32 out.

template <int DIM, int NSLICE, int MODE>
__global__ __launch_bounds__(256) void k_gather_slice(const ushort_t* __restrict__ h,
                                                      const float* __restrict__ dinv,
                                                      const int* __restrict__ offs,
                                                      const int* __restrict__ ebuf,
                                                      const float* __restrict__ bias,
                                                      void* __restrict__ outv, int n) {
    const int slice = blockIdx.x % NSLICE;
    const int node = (blockIdx.x / NSLICE) * 16 + (threadIdx.x >> 4);
    if (node >= n) return;
    const int ld = threadIdx.x & 15;
    const int base = slice * 32 + ld * 2;   // element offset within row
    const ushort_t* hb = h + base;

    float a0, a1;
    {
        const unsigned us = *(const unsigned*)(hb + (size_t)node * DIM);
        a0 = blo(us); a1 = bhi(us);
    }

    int e = offs[node];
    const int e1 = offs[node + 1];
    while (e < e1) {  // deg padded to multiple of 16 -> full 8-batches
        const int i0 = ebuf[e + 0];
        const int i1 = ebuf[e + 1];
        const int i2 = ebuf[e + 2];
        const int i3 = ebuf[e + 3];
        const int i4 = ebuf[e + 4];
        const int i5 = ebuf[e + 5];
        const int i6 = ebuf[e + 6];
        const int i7 = ebuf[e + 7];
        const unsigned u0 = *(const unsigned*)(hb + (size_t)i0 * DIM);
        const unsigned u1 = *(const unsigned*)(hb + (size_t)i1 * DIM);
        const unsigned u2 = *(const unsigned*)(hb + (size_t)i2 * DIM);
        const unsigned u3 = *(const unsigned*)(hb + (size_t)i3 * DIM);
        const unsigned u4 = *(const unsigned*)(hb + (size_t)i4 * DIM);
        const unsigned u5 = *(const unsigned*)(hb + (size_t)i5 * DIM);
        const unsigned u6 = *(const unsigned*)(hb + (size_t)i6 * DIM);
        const unsigned u7 = *(const unsigned*)(hb + (size_t)i7 * DIM);
        a0 += blo(u0); a1 += bhi(u0);
        a0 += blo(u1); a1 += bhi(u1);
        a0 += blo(u2); a1 += bhi(u2);
        a0 += blo(u3); a1 += bhi(u3);
        a0 += blo(u4); a1 += bhi(u4);
        a0 += blo(u5); a1 += bhi(u5);
        a0 += blo(u6); a1 += bhi(u6);
        a0 += blo(u7); a1 += bhi(u7);
        e += 8;
    }

    const float di = dinv[node];
    const float2 bv = *(const float2*)(bias + base);
    if (MODE == 0) {
        const float v0 = fmaxf(di * a0 + bv.x, 0.f);
        const float v1 = fmaxf(di * a1 + bv.y, 0.f);
        ushort_t* out = (ushort_t*)outv;
        *(unsigned*)(out + (size_t)node * DIM + base) = pack2bf(v0, v1);
    } else {
        float2 r;
        r.x = 1.0f / (1.0f + expf(-(di * a0 + bv.x)));
        r.y = 1.0f / (1.0f + expf(-(di * a1 + bv.y)));
        float* out = (float*)outv;
        *(float2*)(out + (size_t)node * DIM + base) = r;
    }
}

// ================= launch =================

extern "C" void kernel_launch(void* const* d_in, const int* in_sizes, int n_in,
                              void* d_out, int out_size, void* d_ws, size_t ws_size,
                              hipStream_t stream) {
    const float* x  = (const float*)d_in[0];
    const int*   ei = (const int*)d_in[1];
    const float* W1 = (const float*)d_in[2];
    const float* b1 = (const float*)d_in[3];
    const float* W2 = (const float*)d_in[4];
    const float* b2 = (const float*)d_in[5];
    float* out = (float*)d_out;

    float* wsf    = (float*)d_ws;
    float* dinv   = wsf;                            // [50048] f32
    int*   degI   = (int*)(wsf + 50048);            // [50048]
    int*   offs   = degI + 50048;                   // [50064] (uses 50001)
    int*   cursor = offs + 50064;                   // [50048]
    int*   bsum   = cursor + 50048;                 // [256]
    int*   ebuf   = bsum + 256;                     // [1600000] padded CSR (<=1.55M used)
    ushort_t* Wt1 = (ushort_t*)(ebuf + 1600000);    // [65536] bf16
    ushort_t* Wt2 = Wt1 + 65536;                    // [32768] bf16
    ushort_t* h1  = Wt2 + 32768;                    // [50048*256] bf16, row 50000 = zeros
    ushort_t* agg1= h1 + (size_t)50048 * D_HID;     // [50048*256] bf16
    ushort_t* h2  = agg1 + (size_t)50048 * D_HID;   // [50048*128] bf16, row 50000 = zeros

    const int* src = ei;
    const int* dst = ei + N_EDGES;

    const int blocksN = (N_NODES + 255) / 256;  // 196
    const int blocksE = (N_EDGES + 255) / 256;

    // ---- CSR build (padded to 16) + norms ----
    hipMemsetAsync(degI, 0, N_NODES * sizeof(int), stream);
    k_count<<<blocksE, 256, 0, stream>>>(dst, degI, N_EDGES);
    k_block_sums<<<blocksN, 256, 0, stream>>>(degI, bsum, N_NODES);
    k_scan_bsums<<<1, 256, 0, stream>>>(bsum, blocksN);
    k_scan_apply<<<blocksN, 256, 0, stream>>>(degI, bsum, offs, cursor, dinv, ebuf, N_NODES);
    k_fill<<<blocksE, 256, 0, stream>>>(src, dst, cursor, ebuf, N_EDGES);

    // ---- weights + zero rows ----
    {
        const int tot = D_IN * D_HID + D_HID * D_OUT + D_HID + D_OUT;
        k_convW<<<(tot + 255) / 256, 256, 0, stream>>>(W1, W2, Wt1, Wt2,
                                                       h1 + (size_t)N_NODES * D_HID,
                                                       h2 + (size_t)N_NODES * D_OUT);
    }

    // ---- layer 1 GEMM: h1 = bf16((x @ W1) * dinv[row]) ----
    {
        dim3 g((N_NODES + 127) / 128, D_HID / 128);
        k_gemm_mfma<false><<<g, 256, 0, stream>>>(x, Wt1, dinv, h1, N_NODES, D_IN, D_HID);
    }

    // ---- aggregate 256-dim (8 slices): agg1 = bf16(relu(dinv*(sum) + b1)) ----
    {
        const int nb = (N_NODES + 15) / 16;  // 3125
        k_gather_slice<D_HID, 8, 0><<<nb * 8, 256, 0, stream>>>(
            h1, dinv, offs, ebuf, b1, agg1, N_NODES);
    }

    // ---- layer 2 GEMM: h2 = bf16((agg1 @ W2) * dinv[row]) ----
    {
        dim3 g((N_NODES + 127) / 128, D_OUT / 128);
        k_gemm_mfma<true><<<g, 256, 0, stream>>>(agg1, Wt2, dinv, h2, N_NODES, D_HID, D_OUT);
    }

    // ---- aggregate 128-dim (4 slices): out = sigmoid(dinv*(sum) + b2) ----
    {
        const int nb = (N_NODES + 15) / 16;  // 3125
        k_gather_slice<D_OUT, 4, 1><<<nb * 4, 256, 0, stream>>>(
            h2, dinv, offs, ebuf, b2, out, N_NODES);
    }
}